// Round 2
// baseline (1313.337 us; speedup 1.0000x reference)
//
#include <hip/hip_runtime.h>

typedef __bf16 bf16;
typedef __bf16 bf16x4 __attribute__((ext_vector_type(4)));
typedef __bf16 bf16x8 __attribute__((ext_vector_type(8)));
typedef float f32x4 __attribute__((ext_vector_type(4)));
typedef float f32x16 __attribute__((ext_vector_type(16)));

#define NEGF (-1e9f)

// async global->LDS, 16B per lane. LDS dest must be wave-uniform-base + lane*16.
__device__ __forceinline__ void gload16(const void* g, void* l) {
  __builtin_amdgcn_global_load_lds(
      (__attribute__((address_space(1))) void*)(void*)g,
      (__attribute__((address_space(3))) void*)l, 16, 0, 0);
}

// ---------------------------------------------------------------------------
// prep: cast x and weights to bf16 (fold log2(e)/sqrt(dk) into w_q), build
// additive key-mask array.
// ---------------------------------------------------------------------------
__global__ __launch_bounds__(256)
void prep_kernel(const float* __restrict__ x, const int* __restrict__ mask,
                 const float* __restrict__ wq, const float* __restrict__ wk,
                 const float* __restrict__ wv, const float* __restrict__ wo,
                 bf16* __restrict__ xb, bf16* __restrict__ wqb,
                 bf16* __restrict__ wkb, bf16* __restrict__ wvb,
                 bf16* __restrict__ wob, float* __restrict__ maskadd)
{
  const float QS = 1.44269504f * 0.08838834764f;  // log2(e)/sqrt(128)
  const size_t i = ((size_t)blockIdx.x * 256 + threadIdx.x) * 4;
  if (i < (size_t)16777216) {
    const float4 v = *(const float4*)&x[i];
    bf16x4 o4 = {(bf16)v.x, (bf16)v.y, (bf16)v.z, (bf16)v.w};
    *(bf16x4*)&xb[i] = o4;
  }
  if (i < (size_t)4194304) {
    float4 v = *(const float4*)&wq[i];
    bf16x4 o4 = {(bf16)(v.x * QS), (bf16)(v.y * QS), (bf16)(v.z * QS), (bf16)(v.w * QS)};
    *(bf16x4*)&wqb[i] = o4;
    v = *(const float4*)&wk[i];
    bf16x4 o5 = {(bf16)v.x, (bf16)v.y, (bf16)v.z, (bf16)v.w};
    *(bf16x4*)&wkb[i] = o5;
    v = *(const float4*)&wv[i];
    bf16x4 o6 = {(bf16)v.x, (bf16)v.y, (bf16)v.z, (bf16)v.w};
    *(bf16x4*)&wvb[i] = o6;
    v = *(const float4*)&wo[i];
    bf16x4 o7 = {(bf16)v.x, (bf16)v.y, (bf16)v.z, (bf16)v.w};
    *(bf16x4*)&wob[i] = o7;
  }
  if (i < (size_t)8192) {
    const int4 m4 = *(const int4*)&mask[i];
    float4 o4 = {m4.x ? 0.f : NEGF, m4.y ? 0.f : NEGF,
                 m4.z ? 0.f : NEGF, m4.w ? 0.f : NEGF};
    *(float4*)&maskadd[i] = o4;
  }
}

// ---------------------------------------------------------------------------
// GEMM core: C[256x128 tile] = A[M,K] @ Bt[N,K]^T, bf16 in, fp32 acc.
// 4 waves, wave tile 128x64, mfma_f32_32x32x16_bf16, BK=64.
// ---------------------------------------------------------------------------
__device__ __forceinline__ void gemm_core(
    const bf16* __restrict__ A, const bf16* __restrict__ Bt, int K,
    int rowBase, int colBase, bf16* As, bf16* Bs, f32x16 acc[4][2])
{
  const int t = threadIdx.x;
  const int lane = t & 63;
  const int w = t >> 6;
  const int wm = (w >> 1) << 7;   // 0 / 128
  const int wn = (w & 1) << 6;    // 0 / 64
  const int l31 = lane & 31;
  const int half = lane >> 5;

  for (int k0 = 0; k0 < K; k0 += 64) {
    __syncthreads();
#pragma unroll
    for (int i = 0; i < 8; ++i) {           // A tile: 256x64 bf16 = 32KB
      const int c = (i << 8) + t;
      const int row = c >> 3;
      const int col = ((c & 7) ^ (row & 7)) << 3;
      gload16(&A[(rowBase + row) * K + k0 + col], &As[c << 3]);
    }
#pragma unroll
    for (int i = 0; i < 4; ++i) {           // B tile: 128x64 bf16 = 16KB
      const int c = (i << 8) + t;
      const int row = c >> 3;
      const int col = ((c & 7) ^ (row & 7)) << 3;
      gload16(&Bt[(colBase + row) * K + k0 + col], &Bs[c << 3]);
    }
    __syncthreads();
#pragma unroll
    for (int kk = 0; kk < 4; ++kk) {        // 4 x k=16 steps
      const int gd = (kk << 1) | half;
      bf16x8 a[4], bfr[2];
#pragma unroll
      for (int mi = 0; mi < 4; ++mi) {
        const int row = wm + (mi << 5) + l31;
        a[mi] = *(const bf16x8*)&As[(row << 6) + ((gd ^ (row & 7)) << 3)];
      }
#pragma unroll
      for (int ni = 0; ni < 2; ++ni) {
        const int row = wn + (ni << 5) + l31;
        bfr[ni] = *(const bf16x8*)&Bs[(row << 6) + ((gd ^ (row & 7)) << 3)];
      }
#pragma unroll
      for (int mi = 0; mi < 4; ++mi)
#pragma unroll
        for (int ni = 0; ni < 2; ++ni)
          acc[mi][ni] = __builtin_amdgcn_mfma_f32_32x32x16_bf16(
              a[mi], bfr[ni], acc[mi][ni], 0, 0, 0);
    }
  }
}

// QKV projection: x@W^T, epilogue scatters into per-head layouts.
__global__ __launch_bounds__(256, 2)
void qkv_gemm_kernel(const bf16* __restrict__ xb,
                     const bf16* __restrict__ wqb, const bf16* __restrict__ wkb,
                     const bf16* __restrict__ wvb,
                     bf16* __restrict__ qb, bf16* __restrict__ kb,
                     bf16* __restrict__ vtb)
{
  __shared__ __align__(16) bf16 As[256 * 64];
  __shared__ __align__(16) bf16 Bs[128 * 64];
  const int z = blockIdx.z;
  const bf16* Bt = (z == 0) ? wqb : (z == 1) ? wkb : wvb;
  bf16* dst = (z == 0) ? qb : (z == 1) ? kb : vtb;
  const int rowBase = blockIdx.y << 8;
  const int colBase = blockIdx.x << 7;
  f32x16 acc[4][2];
#pragma unroll
  for (int mi = 0; mi < 4; ++mi)
#pragma unroll
    for (int ni = 0; ni < 2; ++ni)
#pragma unroll
      for (int e = 0; e < 16; ++e) acc[mi][ni][e] = 0.f;

  gemm_core(xb, Bt, 2048, rowBase, colBase, As, Bs, acc);

  const int lane = threadIdx.x & 63;
  const int w = threadIdx.x >> 6;
  const int wm = (w >> 1) << 7;
  const int wn = (w & 1) << 6;
  const int l31 = lane & 31;
  const int half = lane >> 5;
#pragma unroll
  for (int mi = 0; mi < 4; ++mi)
#pragma unroll
    for (int ni = 0; ni < 2; ++ni)
#pragma unroll
      for (int r = 0; r < 16; ++r) {
        const int row = rowBase + wm + (mi << 5) + (r & 3) + ((r >> 2) << 3) + (half << 2);
        const int col = colBase + wn + (ni << 5) + l31;
        const int b = row >> 11, s = row & 2047;
        const int h = col >> 7, d = col & 127;
        const bf16 v = (bf16)acc[mi][ni][r];
        if (z == 2) dst[((((b << 4) + h) << 7) + d) * 2048 + s] = v;
        else        dst[(((((b << 4) + h) << 11) + s) << 7) + d] = v;
      }
}

// final projection: attn @ w_o^T -> fp32 d_out
__global__ __launch_bounds__(256, 2)
void out_gemm_kernel(const bf16* __restrict__ attnb, const bf16* __restrict__ wob,
                     float* __restrict__ out)
{
  __shared__ __align__(16) bf16 As[256 * 64];
  __shared__ __align__(16) bf16 Bs[128 * 64];
  const int rowBase = blockIdx.y << 8;
  const int colBase = blockIdx.x << 7;
  f32x16 acc[4][2];
#pragma unroll
  for (int mi = 0; mi < 4; ++mi)
#pragma unroll
    for (int ni = 0; ni < 2; ++ni)
#pragma unroll
      for (int e = 0; e < 16; ++e) acc[mi][ni][e] = 0.f;

  gemm_core(attnb, wob, 2048, rowBase, colBase, As, Bs, acc);

  const int lane = threadIdx.x & 63;
  const int w = threadIdx.x >> 6;
  const int wm = (w >> 1) << 7;
  const int wn = (w & 1) << 6;
  const int l31 = lane & 31;
  const int half = lane >> 5;
#pragma unroll
  for (int mi = 0; mi < 4; ++mi)
#pragma unroll
    for (int ni = 0; ni < 2; ++ni)
#pragma unroll
      for (int r = 0; r < 16; ++r) {
        const int row = rowBase + wm + (mi << 5) + (r & 3) + ((r >> 2) << 3) + (half << 2);
        const int col = colBase + wn + (ni << 5) + l31;
        out[((size_t)row << 11) + col] = acc[mi][ni][r];
      }
}

// ---------------------------------------------------------------------------
// flash attention, fixed-max softmax (scores bounded -> m=0, no per-tile
// reductions). P-transpose buffer ALIASES the K-tile (extra barrier).
// LDS = 32KB -> 4 blocks/CU. qt reversed so long blocks dispatch first.
// ---------------------------------------------------------------------------
__global__ __launch_bounds__(256, 4)
void flash_kernel(const bf16* __restrict__ qb, const bf16* __restrict__ kb,
                  const bf16* __restrict__ vtb, const float* __restrict__ maskadd,
                  bf16* __restrict__ attnb)
{
  __shared__ __align__(16) bf16 Ks[64 * 128];   // K tile; re-used as P after QK
  __shared__ __align__(16) bf16 Vs[128 * 64];   // V^T tile

  const int qt = 15 - (int)blockIdx.x;          // long blocks first
  const int h = blockIdx.y, b = blockIdx.z;
  const int t = threadIdx.x, lane = t & 63, w = t >> 6;
  const int quad = lane >> 4, l15 = lane & 15;
  const int bh = (b << 4) + h;
  const bf16* Qp = qb + (size_t)bh * (2048 * 128);
  const bf16* Kp = kb + (size_t)bh * (2048 * 128);
  const bf16* Vp = vtb + (size_t)bh * (128 * 2048);
  const int qrow0 = (qt << 7) + (w << 5);

  // Q fragments (A layout: m=l15, k=quad*8+j), log2-scaled already
  bf16x8 qf[2][4];
#pragma unroll
  for (int mi = 0; mi < 2; ++mi)
#pragma unroll
    for (int kk = 0; kk < 4; ++kk)
      qf[mi][kk] = *(const bf16x8*)&Qp[((qrow0 + (mi << 4) + l15) << 7) + (kk << 5) + (quad << 3)];

  f32x4 o[2][8];
  float lpart[2][4];
#pragma unroll
  for (int mi = 0; mi < 2; ++mi)
#pragma unroll
    for (int r = 0; r < 4; ++r) lpart[mi][r] = 0.f;
#pragma unroll
  for (int mi = 0; mi < 2; ++mi)
#pragma unroll
    for (int dj = 0; dj < 8; ++dj)
#pragma unroll
      for (int r = 0; r < 4; ++r) o[mi][dj][r] = 0.f;

  bf16* Pw = &Ks[w << 11];   // per-wave 32x64 P region (stride 64, XOR swizzle)
  const int nkt = (qt << 1) + 2;
  for (int kt = 0; kt < nkt; ++kt) {
    __syncthreads();                        // prior P/V reads done
#pragma unroll
    for (int i = 0; i < 4; ++i) {           // K tile 64x128
      const int c = (i << 8) + t;
      const int row = c >> 4;
      const int col = ((c & 15) ^ (row & 15)) << 3;
      gload16(&Kp[(((kt << 6) + row) << 7) + col], &Ks[c << 3]);
    }
#pragma unroll
    for (int i = 0; i < 4; ++i) {           // V^T tile 128x64
      const int c = (i << 8) + t;
      const int row = c >> 3;
      const int col = ((c & 7) ^ (row & 7)) << 3;
      gload16(&Vp[(row << 11) + (kt << 6) + col], &Vs[c << 3]);
    }
    __syncthreads();                        // tiles visible

    const bool skip = (kt << 6) > qrow0 + 31;
    f32x4 S[2][4];
    if (!skip) {
      // S = Q @ K^T (log2 domain)
#pragma unroll
      for (int mi = 0; mi < 2; ++mi)
#pragma unroll
        for (int nj = 0; nj < 4; ++nj)
#pragma unroll
          for (int r = 0; r < 4; ++r) S[mi][nj][r] = 0.f;
#pragma unroll
      for (int kk = 0; kk < 4; ++kk) {
        bf16x8 kf[4];
#pragma unroll
        for (int nj = 0; nj < 4; ++nj) {
          const int key = (nj << 4) + l15;
          const int gd = (kk << 2) + quad;
          kf[nj] = *(const bf16x8*)&Ks[(key << 7) + ((gd ^ (key & 15)) << 3)];
        }
#pragma unroll
        for (int mi = 0; mi < 2; ++mi)
#pragma unroll
          for (int nj = 0; nj < 4; ++nj)
            S[mi][nj] = __builtin_amdgcn_mfma_f32_16x16x32_bf16(qf[mi][kk], kf[nj], S[mi][nj], 0, 0, 0);
      }
      // mask + causal + exp2 (m=0 fixed), accumulate l partials
      float mv[4];
#pragma unroll
      for (int nj = 0; nj < 4; ++nj)
        mv[nj] = maskadd[(b << 11) + (kt << 6) + (nj << 4) + l15];
      const bool diag = ((kt << 6) + 63 > qrow0);
#pragma unroll
      for (int mi = 0; mi < 2; ++mi)
#pragma unroll
        for (int nj = 0; nj < 4; ++nj)
#pragma unroll
          for (int r = 0; r < 4; ++r) {
            float s = S[mi][nj][r] + mv[nj];
            if (diag) {
              const int key = (kt << 6) + (nj << 4) + l15;
              const int qrow = qrow0 + (mi << 4) + (quad << 2) + r;
              if (key > qrow) s += NEGF;
            }
            const float p = __builtin_amdgcn_exp2f(s);
            S[mi][nj][r] = p;
            lpart[mi][r] += p;
          }
    }
    __syncthreads();                        // all waves done reading Ks
    if (!skip) {
      // P -> LDS (C-layout write, XOR-swizzled stride 64), wave-local
#pragma unroll
      for (int mi = 0; mi < 2; ++mi)
#pragma unroll
        for (int nj = 0; nj < 4; ++nj)
#pragma unroll
          for (int r = 0; r < 4; ++r) {
            const int row = (mi << 4) + (quad << 2) + r;
            const int col = (nj << 4) + l15;
            Pw[(row << 6) + ((((col >> 3) ^ (row & 7)) << 3) | (col & 7))] = (bf16)S[mi][nj][r];
          }
      // read back in A layout, PV mfmas
#pragma unroll
      for (int kk = 0; kk < 2; ++kk) {
        bf16x8 pf[2];
#pragma unroll
        for (int mi = 0; mi < 2; ++mi) {
          const int row = (mi << 4) + l15;
          pf[mi] = *(const bf16x8*)&Pw[(row << 6) + ((((kk << 2) + quad) ^ (row & 7)) << 3)];
        }
#pragma unroll
        for (int dj = 0; dj < 8; ++dj) {
          const int d = (dj << 4) + l15;
          const int gd = (kk << 2) + quad;
          const bf16x8 vf = *(const bf16x8*)&Vs[(d << 6) + ((gd ^ (d & 7)) << 3)];
#pragma unroll
          for (int mi = 0; mi < 2; ++mi)
            o[mi][dj] = __builtin_amdgcn_mfma_f32_16x16x32_bf16(pf[mi], vf, o[mi][dj], 0, 0, 0);
        }
      }
    }
  }

  // one-time l reduction across the 16 lanes holding each row's columns
#pragma unroll
  for (int mi = 0; mi < 2; ++mi)
#pragma unroll
    for (int r = 0; r < 4; ++r) {
      float s = lpart[mi][r];
#pragma unroll
      for (int off = 1; off < 16; off <<= 1) s += __shfl_xor(s, off);
      const float inv = 1.0f / s;   // l==0 rows produce NaN; fixup overwrites them
      const int row = qrow0 + (mi << 4) + (quad << 2) + r;
#pragma unroll
      for (int dj = 0; dj < 8; ++dj) {
        const int d = (dj << 4) + l15;
        attnb[((size_t)((b << 11) + row) << 11) + (h << 7) + d] = (bf16)(o[mi][dj][r] * inv);
      }
    }
}

// ---------------------------------------------------------------------------
// degenerate-row handling: rows q < first_nonzero(mask[b]) have ALL scores
// masked in the reference -> softmax uniform over all 2048 keys -> mean(V).
// ---------------------------------------------------------------------------
__global__ void scan_mask_kernel(const int* __restrict__ mask, int* __restrict__ firstone)
{
  __shared__ int fm;
  for (int b = 0; b < 4; ++b) {
    if (threadIdx.x == 0) fm = 2048;
    __syncthreads();
    int lm = 2048;
    for (int s = threadIdx.x; s < 2048; s += 256)
      if (mask[(b << 11) + s] != 0) lm = min(lm, s);
    atomicMin(&fm, lm);
    __syncthreads();
    if (threadIdx.x == 0) firstone[b] = fm;
    __syncthreads();
  }
}

__global__ void mean_v_kernel(const bf16* __restrict__ vtb, float* __restrict__ meanv)
{
  const int row = blockIdx.x;  // bh*128 + d, 8192 rows
  float sum = 0.f;
  for (int s = threadIdx.x; s < 2048; s += 256)
    sum += (float)vtb[((size_t)row << 11) + s];
#pragma unroll
  for (int off = 1; off < 64; off <<= 1) sum += __shfl_xor(sum, off);
  __shared__ float part[4];
  if ((threadIdx.x & 63) == 0) part[threadIdx.x >> 6] = sum;
  __syncthreads();
  if (threadIdx.x == 0)
    meanv[row] = (part[0] + part[1] + part[2] + part[3]) * (1.0f / 2048.0f);
}

__global__ void fixup_kernel(const int* __restrict__ firstone,
                             const float* __restrict__ meanv,
                             bf16* __restrict__ attnb)
{
  const int b = blockIdx.x, h = blockIdx.y, d = threadIdx.x;  // 128 threads
  const int f = firstone[b];
  const bf16 v = (bf16)meanv[(((b << 4) + h) << 7) + d];
  for (int s = 0; s < f; ++s)
    attnb[((size_t)((b << 11) + s) << 11) + (h << 7) + d] = v;
}

// ---------------------------------------------------------------------------
extern "C" void kernel_launch(void* const* d_in, const int* in_sizes, int n_in,
                              void* d_out, int out_size, void* d_ws, size_t ws_size,
                              hipStream_t stream)
{
  const float* x  = (const float*)d_in[0];
  const int* mask = (const int*)d_in[1];
  const float* wq = (const float*)d_in[2];
  const float* wk = (const float*)d_in[3];
  const float* wv = (const float*)d_in[4];
  const float* wo = (const float*)d_in[5];
  float* out = (float*)d_out;

  char* ws = (char*)d_ws;
  bf16* xb      = (bf16*)(ws + 0);            // 33554432
  bf16* wqb     = (bf16*)(ws + 33554432);     //  8388608
  bf16* wkb     = (bf16*)(ws + 41943040);     //  8388608
  bf16* wvb     = (bf16*)(ws + 50331648);     //  8388608
  bf16* wob     = (bf16*)(ws + 58720256);     //  8388608
  bf16* qb      = (bf16*)(ws + 67108864);     // 33554432
  bf16* kb      = (bf16*)(ws + 100663296);    // 33554432
  bf16* vtb     = (bf16*)(ws + 134217728);    // 33554432
  bf16* attnb   = (bf16*)(ws + 167772160);    // 33554432
  float* maskadd= (float*)(ws + 201326592);   //    32768
  float* meanv  = (float*)(ws + 201359360);   //    32768
  int* firstone = (int*)(ws + 201392128);     //       16

  prep_kernel<<<16384, 256, 0, stream>>>(x, mask, wq, wk, wv, wo,
                                         xb, wqb, wkb, wvb, wob, maskadd);
  qkv_gemm_kernel<<<dim3(16, 32, 3), 256, 0, stream>>>(xb, wqb, wkb, wvb, qb, kb, vtb);
  scan_mask_kernel<<<1, 256, 0, stream>>>(mask, firstone);
  mean_v_kernel<<<8192, 256, 0, stream>>>(vtb, meanv);
  flash_kernel<<<dim3(16, 16, 4), 256, 0, stream>>>(qb, kb, vtb, maskadd, attnb);
  fixup_kernel<<<dim3(4, 16), 128, 0, stream>>>(firstone, meanv, attnb);
  out_gemm_kernel<<<dim3(16, 32), 256, 0, stream>>>(attnb, wob, out);
}

// Round 3
// 689.865 us; speedup vs baseline: 1.9038x; 1.9038x over previous
//
#include <hip/hip_runtime.h>

typedef __bf16 bf16;
typedef __bf16 bf16x4 __attribute__((ext_vector_type(4)));
typedef __bf16 bf16x8 __attribute__((ext_vector_type(8)));
typedef float f32x4 __attribute__((ext_vector_type(4)));
typedef float f32x16 __attribute__((ext_vector_type(16)));

#define NEGF (-1e9f)

// async global->LDS, 16B per lane. LDS dest must be wave-uniform-base + lane*16.
__device__ __forceinline__ void gload16(const void* g, void* l) {
  __builtin_amdgcn_global_load_lds(
      (__attribute__((address_space(1))) void*)(void*)g,
      (__attribute__((address_space(3))) void*)l, 16, 0, 0);
}

// ---------------------------------------------------------------------------
// prep: cast x and weights to bf16 (fold log2(e)/sqrt(dk) into w_q), build
// additive key-mask array.
// ---------------------------------------------------------------------------
__global__ __launch_bounds__(256)
void prep_kernel(const float* __restrict__ x, const int* __restrict__ mask,
                 const float* __restrict__ wq, const float* __restrict__ wk,
                 const float* __restrict__ wv, const float* __restrict__ wo,
                 bf16* __restrict__ xb, bf16* __restrict__ wqb,
                 bf16* __restrict__ wkb, bf16* __restrict__ wvb,
                 bf16* __restrict__ wob, float* __restrict__ maskadd)
{
  const float QS = 1.44269504f * 0.08838834764f;  // log2(e)/sqrt(128)
  const size_t i = ((size_t)blockIdx.x * 256 + threadIdx.x) * 4;
  if (i < (size_t)16777216) {
    const float4 v = *(const float4*)&x[i];
    bf16x4 o4 = {(bf16)v.x, (bf16)v.y, (bf16)v.z, (bf16)v.w};
    *(bf16x4*)&xb[i] = o4;
  }
  if (i < (size_t)4194304) {
    float4 v = *(const float4*)&wq[i];
    bf16x4 o4 = {(bf16)(v.x * QS), (bf16)(v.y * QS), (bf16)(v.z * QS), (bf16)(v.w * QS)};
    *(bf16x4*)&wqb[i] = o4;
    v = *(const float4*)&wk[i];
    bf16x4 o5 = {(bf16)v.x, (bf16)v.y, (bf16)v.z, (bf16)v.w};
    *(bf16x4*)&wkb[i] = o5;
    v = *(const float4*)&wv[i];
    bf16x4 o6 = {(bf16)v.x, (bf16)v.y, (bf16)v.z, (bf16)v.w};
    *(bf16x4*)&wvb[i] = o6;
    v = *(const float4*)&wo[i];
    bf16x4 o7 = {(bf16)v.x, (bf16)v.y, (bf16)v.z, (bf16)v.w};
    *(bf16x4*)&wob[i] = o7;
  }
  if (i < (size_t)8192) {
    const int4 m4 = *(const int4*)&mask[i];
    float4 o4 = {m4.x ? 0.f : NEGF, m4.y ? 0.f : NEGF,
                 m4.z ? 0.f : NEGF, m4.w ? 0.f : NEGF};
    *(float4*)&maskadd[i] = o4;
  }
}

// ---------------------------------------------------------------------------
// GEMM core: C[256x128 tile] = A[M,K] @ Bt[N,K]^T, bf16 in, fp32 acc.
// 4 waves, wave tile 128x64, mfma_f32_32x32x16_bf16, BK=64.
// ---------------------------------------------------------------------------
__device__ __forceinline__ void gemm_core(
    const bf16* __restrict__ A, const bf16* __restrict__ Bt, int K,
    int rowBase, int colBase, bf16* As, bf16* Bs, f32x16 acc[4][2])
{
  const int t = threadIdx.x;
  const int lane = t & 63;
  const int w = t >> 6;
  const int wm = (w >> 1) << 7;   // 0 / 128
  const int wn = (w & 1) << 6;    // 0 / 64
  const int l31 = lane & 31;
  const int half = lane >> 5;

  for (int k0 = 0; k0 < K; k0 += 64) {
    __syncthreads();
#pragma unroll
    for (int i = 0; i < 8; ++i) {           // A tile: 256x64 bf16 = 32KB
      const int c = (i << 8) + t;
      const int row = c >> 3;
      const int col = ((c & 7) ^ (row & 7)) << 3;
      gload16(&A[(rowBase + row) * K + k0 + col], &As[c << 3]);
    }
#pragma unroll
    for (int i = 0; i < 4; ++i) {           // B tile: 128x64 bf16 = 16KB
      const int c = (i << 8) + t;
      const int row = c >> 3;
      const int col = ((c & 7) ^ (row & 7)) << 3;
      gload16(&Bt[(colBase + row) * K + k0 + col], &Bs[c << 3]);
    }
    __syncthreads();
#pragma unroll
    for (int kk = 0; kk < 4; ++kk) {        // 4 x k=16 steps
      const int gd = (kk << 1) | half;
      bf16x8 a[4], bfr[2];
#pragma unroll
      for (int mi = 0; mi < 4; ++mi) {
        const int row = wm + (mi << 5) + l31;
        a[mi] = *(const bf16x8*)&As[(row << 6) + ((gd ^ (row & 7)) << 3)];
      }
#pragma unroll
      for (int ni = 0; ni < 2; ++ni) {
        const int row = wn + (ni << 5) + l31;
        bfr[ni] = *(const bf16x8*)&Bs[(row << 6) + ((gd ^ (row & 7)) << 3)];
      }
#pragma unroll
      for (int mi = 0; mi < 4; ++mi)
#pragma unroll
        for (int ni = 0; ni < 2; ++ni)
          acc[mi][ni] = __builtin_amdgcn_mfma_f32_32x32x16_bf16(
              a[mi], bfr[ni], acc[mi][ni], 0, 0, 0);
    }
  }
}

// QKV projection: x@W^T, epilogue scatters into per-head layouts.
__global__ __launch_bounds__(256, 2)
void qkv_gemm_kernel(const bf16* __restrict__ xb,
                     const bf16* __restrict__ wqb, const bf16* __restrict__ wkb,
                     const bf16* __restrict__ wvb,
                     bf16* __restrict__ qb, bf16* __restrict__ kb,
                     bf16* __restrict__ vtb)
{
  __shared__ __align__(16) bf16 As[256 * 64];
  __shared__ __align__(16) bf16 Bs[128 * 64];
  const int z = blockIdx.z;
  const bf16* Bt = (z == 0) ? wqb : (z == 1) ? wkb : wvb;
  bf16* dst = (z == 0) ? qb : (z == 1) ? kb : vtb;
  const int rowBase = blockIdx.y << 8;
  const int colBase = blockIdx.x << 7;
  f32x16 acc[4][2];
#pragma unroll
  for (int mi = 0; mi < 4; ++mi)
#pragma unroll
    for (int ni = 0; ni < 2; ++ni)
#pragma unroll
      for (int e = 0; e < 16; ++e) acc[mi][ni][e] = 0.f;

  gemm_core(xb, Bt, 2048, rowBase, colBase, As, Bs, acc);

  const int lane = threadIdx.x & 63;
  const int w = threadIdx.x >> 6;
  const int wm = (w >> 1) << 7;
  const int wn = (w & 1) << 6;
  const int l31 = lane & 31;
  const int half = lane >> 5;
#pragma unroll
  for (int mi = 0; mi < 4; ++mi)
#pragma unroll
    for (int ni = 0; ni < 2; ++ni)
#pragma unroll
      for (int r = 0; r < 16; ++r) {
        const int row = rowBase + wm + (mi << 5) + (r & 3) + ((r >> 2) << 3) + (half << 2);
        const int col = colBase + wn + (ni << 5) + l31;
        const int b = row >> 11, s = row & 2047;
        const int h = col >> 7, d = col & 127;
        const bf16 v = (bf16)acc[mi][ni][r];
        if (z == 2) dst[((((b << 4) + h) << 7) + d) * 2048 + s] = v;
        else        dst[(((((b << 4) + h) << 11) + s) << 7) + d] = v;
      }
}

// final projection: attn @ w_o^T -> fp32 d_out
__global__ __launch_bounds__(256, 2)
void out_gemm_kernel(const bf16* __restrict__ attnb, const bf16* __restrict__ wob,
                     float* __restrict__ out)
{
  __shared__ __align__(16) bf16 As[256 * 64];
  __shared__ __align__(16) bf16 Bs[128 * 64];
  const int rowBase = blockIdx.y << 8;
  const int colBase = blockIdx.x << 7;
  f32x16 acc[4][2];
#pragma unroll
  for (int mi = 0; mi < 4; ++mi)
#pragma unroll
    for (int ni = 0; ni < 2; ++ni)
#pragma unroll
      for (int e = 0; e < 16; ++e) acc[mi][ni][e] = 0.f;

  gemm_core(attnb, wob, 2048, rowBase, colBase, As, Bs, acc);

  const int lane = threadIdx.x & 63;
  const int w = threadIdx.x >> 6;
  const int wm = (w >> 1) << 7;
  const int wn = (w & 1) << 6;
  const int l31 = lane & 31;
  const int half = lane >> 5;
#pragma unroll
  for (int mi = 0; mi < 4; ++mi)
#pragma unroll
    for (int ni = 0; ni < 2; ++ni)
#pragma unroll
      for (int r = 0; r < 16; ++r) {
        const int row = rowBase + wm + (mi << 5) + (r & 3) + ((r >> 2) << 3) + (half << 2);
        const int col = colBase + wn + (ni << 5) + l31;
        out[((size_t)row << 11) + col] = acc[mi][ni][r];
      }
}

// ---------------------------------------------------------------------------
// flash attention, fixed-max softmax (scores bounded -> m=0, no per-tile
// reductions). P-transpose buffer ALIASES the K-tile (extra barrier).
// LDS = 32KB. launch_bounds(256,2): 256-reg cap -> NO spill (the (256,4)
// variant spilled: 845MB scratch writes, 2.7x slower). Occupancy comes from
// actual VGPR (~116 -> 4 waves/SIMD) + LDS (5 blocks/CU) = 4 blocks/CU.
// ---------------------------------------------------------------------------
__global__ __launch_bounds__(256, 2)
void flash_kernel(const bf16* __restrict__ qb, const bf16* __restrict__ kb,
                  const bf16* __restrict__ vtb, const float* __restrict__ maskadd,
                  bf16* __restrict__ attnb)
{
  __shared__ __align__(16) bf16 Ks[64 * 128];   // K tile; re-used as P after QK
  __shared__ __align__(16) bf16 Vs[128 * 64];   // V^T tile

  const int qt = 15 - (int)blockIdx.x;          // long blocks first
  const int h = blockIdx.y, b = blockIdx.z;
  const int t = threadIdx.x, lane = t & 63, w = t >> 6;
  const int quad = lane >> 4, l15 = lane & 15;
  const int bh = (b << 4) + h;
  const bf16* Qp = qb + (size_t)bh * (2048 * 128);
  const bf16* Kp = kb + (size_t)bh * (2048 * 128);
  const bf16* Vp = vtb + (size_t)bh * (128 * 2048);
  const int qrow0 = (qt << 7) + (w << 5);

  // Q fragments (A layout: m=l15, k=quad*8+j), log2-scaled already
  bf16x8 qf[2][4];
#pragma unroll
  for (int mi = 0; mi < 2; ++mi)
#pragma unroll
    for (int kk = 0; kk < 4; ++kk)
      qf[mi][kk] = *(const bf16x8*)&Qp[((qrow0 + (mi << 4) + l15) << 7) + (kk << 5) + (quad << 3)];

  f32x4 o[2][8];
  float lpart[2][4];
#pragma unroll
  for (int mi = 0; mi < 2; ++mi)
#pragma unroll
    for (int r = 0; r < 4; ++r) lpart[mi][r] = 0.f;
#pragma unroll
  for (int mi = 0; mi < 2; ++mi)
#pragma unroll
    for (int dj = 0; dj < 8; ++dj)
#pragma unroll
      for (int r = 0; r < 4; ++r) o[mi][dj][r] = 0.f;

  bf16* Pw = &Ks[w << 11];   // per-wave 32x64 P region (stride 64, XOR swizzle)
  const int nkt = (qt << 1) + 2;
  for (int kt = 0; kt < nkt; ++kt) {
    __syncthreads();                        // prior P/V reads done
#pragma unroll
    for (int i = 0; i < 4; ++i) {           // K tile 64x128
      const int c = (i << 8) + t;
      const int row = c >> 4;
      const int col = ((c & 15) ^ (row & 15)) << 3;
      gload16(&Kp[(((kt << 6) + row) << 7) + col], &Ks[c << 3]);
    }
#pragma unroll
    for (int i = 0; i < 4; ++i) {           // V^T tile 128x64
      const int c = (i << 8) + t;
      const int row = c >> 3;
      const int col = ((c & 7) ^ (row & 7)) << 3;
      gload16(&Vp[(row << 11) + (kt << 6) + col], &Vs[c << 3]);
    }
    __syncthreads();                        // tiles visible

    const bool skip = (kt << 6) > qrow0 + 31;
    f32x4 S[2][4];
    if (!skip) {
      // S = Q @ K^T (log2 domain)
#pragma unroll
      for (int mi = 0; mi < 2; ++mi)
#pragma unroll
        for (int nj = 0; nj < 4; ++nj)
#pragma unroll
          for (int r = 0; r < 4; ++r) S[mi][nj][r] = 0.f;
#pragma unroll
      for (int kk = 0; kk < 4; ++kk) {
        bf16x8 kf[4];
#pragma unroll
        for (int nj = 0; nj < 4; ++nj) {
          const int key = (nj << 4) + l15;
          const int gd = (kk << 2) + quad;
          kf[nj] = *(const bf16x8*)&Ks[(key << 7) + ((gd ^ (key & 15)) << 3)];
        }
#pragma unroll
        for (int mi = 0; mi < 2; ++mi)
#pragma unroll
          for (int nj = 0; nj < 4; ++nj)
            S[mi][nj] = __builtin_amdgcn_mfma_f32_16x16x32_bf16(qf[mi][kk], kf[nj], S[mi][nj], 0, 0, 0);
      }
      // mask + causal + exp2 (m=0 fixed), accumulate l partials
      float mv[4];
#pragma unroll
      for (int nj = 0; nj < 4; ++nj)
        mv[nj] = maskadd[(b << 11) + (kt << 6) + (nj << 4) + l15];
      const bool diag = ((kt << 6) + 63 > qrow0);
#pragma unroll
      for (int mi = 0; mi < 2; ++mi)
#pragma unroll
        for (int nj = 0; nj < 4; ++nj)
#pragma unroll
          for (int r = 0; r < 4; ++r) {
            float s = S[mi][nj][r] + mv[nj];
            if (diag) {
              const int key = (kt << 6) + (nj << 4) + l15;
              const int qrow = qrow0 + (mi << 4) + (quad << 2) + r;
              if (key > qrow) s += NEGF;
            }
            const float p = __builtin_amdgcn_exp2f(s);
            S[mi][nj][r] = p;
            lpart[mi][r] += p;
          }
    }
    __syncthreads();                        // all waves done reading Ks
    if (!skip) {
      // P -> LDS (C-layout write, XOR-swizzled stride 64), wave-local
#pragma unroll
      for (int mi = 0; mi < 2; ++mi)
#pragma unroll
        for (int nj = 0; nj < 4; ++nj)
#pragma unroll
          for (int r = 0; r < 4; ++r) {
            const int row = (mi << 4) + (quad << 2) + r;
            const int col = (nj << 4) + l15;
            Pw[(row << 6) + ((((col >> 3) ^ (row & 7)) << 3) | (col & 7))] = (bf16)S[mi][nj][r];
          }
      // read back in A layout, PV mfmas
#pragma unroll
      for (int kk = 0; kk < 2; ++kk) {
        bf16x8 pf[2];
#pragma unroll
        for (int mi = 0; mi < 2; ++mi) {
          const int row = (mi << 4) + l15;
          pf[mi] = *(const bf16x8*)&Pw[(row << 6) + ((((kk << 2) + quad) ^ (row & 7)) << 3)];
        }
#pragma unroll
        for (int dj = 0; dj < 8; ++dj) {
          const int d = (dj << 4) + l15;
          const int gd = (kk << 2) + quad;
          const bf16x8 vf = *(const bf16x8*)&Vs[(d << 6) + ((gd ^ (d & 7)) << 3)];
#pragma unroll
          for (int mi = 0; mi < 2; ++mi)
            o[mi][dj] = __builtin_amdgcn_mfma_f32_16x16x32_bf16(pf[mi], vf, o[mi][dj], 0, 0, 0);
        }
      }
    }
  }

  // one-time l reduction across the 16 lanes holding each row's columns
#pragma unroll
  for (int mi = 0; mi < 2; ++mi)
#pragma unroll
    for (int r = 0; r < 4; ++r) {
      float s = lpart[mi][r];
#pragma unroll
      for (int off = 1; off < 16; off <<= 1) s += __shfl_xor(s, off);
      const float inv = 1.0f / s;   // l==0 rows produce NaN; fixup overwrites them
      const int row = qrow0 + (mi << 4) + (quad << 2) + r;
#pragma unroll
      for (int dj = 0; dj < 8; ++dj) {
        const int d = (dj << 4) + l15;
        attnb[((size_t)((b << 11) + row) << 11) + (h << 7) + d] = (bf16)(o[mi][dj][r] * inv);
      }
    }
}

// ---------------------------------------------------------------------------
// degenerate-row handling: rows q < first_nonzero(mask[b]) have ALL scores
// masked in the reference -> softmax uniform over all 2048 keys -> mean(V).
// ---------------------------------------------------------------------------
__global__ void scan_mask_kernel(const int* __restrict__ mask, int* __restrict__ firstone)
{
  __shared__ int fm;
  for (int b = 0; b < 4; ++b) {
    if (threadIdx.x == 0) fm = 2048;
    __syncthreads();
    int lm = 2048;
    for (int s = threadIdx.x; s < 2048; s += 256)
      if (mask[(b << 11) + s] != 0) lm = min(lm, s);
    atomicMin(&fm, lm);
    __syncthreads();
    if (threadIdx.x == 0) firstone[b] = fm;
    __syncthreads();
  }
}

__global__ void mean_v_kernel(const bf16* __restrict__ vtb, float* __restrict__ meanv)
{
  const int row = blockIdx.x;  // bh*128 + d, 8192 rows
  float sum = 0.f;
  for (int s = threadIdx.x; s < 2048; s += 256)
    sum += (float)vtb[((size_t)row << 11) + s];
#pragma unroll
  for (int off = 1; off < 64; off <<= 1) sum += __shfl_xor(sum, off);
  __shared__ float part[4];
  if ((threadIdx.x & 63) == 0) part[threadIdx.x >> 6] = sum;
  __syncthreads();
  if (threadIdx.x == 0)
    meanv[row] = (part[0] + part[1] + part[2] + part[3]) * (1.0f / 2048.0f);
}

__global__ void fixup_kernel(const int* __restrict__ firstone,
                             const float* __restrict__ meanv,
                             bf16* __restrict__ attnb)
{
  const int b = blockIdx.x, h = blockIdx.y, d = threadIdx.x;  // 128 threads
  const int f = firstone[b];
  const bf16 v = (bf16)meanv[(((b << 4) + h) << 7) + d];
  for (int s = 0; s < f; ++s)
    attnb[((size_t)((b << 11) + s) << 11) + (h << 7) + d] = v;
}

// ---------------------------------------------------------------------------
extern "C" void kernel_launch(void* const* d_in, const int* in_sizes, int n_in,
                              void* d_out, int out_size, void* d_ws, size_t ws_size,
                              hipStream_t stream)
{
  const float* x  = (const float*)d_in[0];
  const int* mask = (const int*)d_in[1];
  const float* wq = (const float*)d_in[2];
  const float* wk = (const float*)d_in[3];
  const float* wv = (const float*)d_in[4];
  const float* wo = (const float*)d_in[5];
  float* out = (float*)d_out;

  char* ws = (char*)d_ws;
  bf16* xb      = (bf16*)(ws + 0);            // 33554432
  bf16* wqb     = (bf16*)(ws + 33554432);     //  8388608
  bf16* wkb     = (bf16*)(ws + 41943040);     //  8388608
  bf16* wvb     = (bf16*)(ws + 50331648);     //  8388608
  bf16* wob     = (bf16*)(ws + 58720256);     //  8388608
  bf16* qb      = (bf16*)(ws + 67108864);     // 33554432
  bf16* kb      = (bf16*)(ws + 100663296);    // 33554432
  bf16* vtb     = (bf16*)(ws + 134217728);    // 33554432
  bf16* attnb   = (bf16*)(ws + 167772160);    // 33554432
  float* maskadd= (float*)(ws + 201326592);   //    32768
  float* meanv  = (float*)(ws + 201359360);   //    32768
  int* firstone = (int*)(ws + 201392128);     //       16

  prep_kernel<<<16384, 256, 0, stream>>>(x, mask, wq, wk, wv, wo,
                                         xb, wqb, wkb, wvb, wob, maskadd);
  qkv_gemm_kernel<<<dim3(16, 32, 3), 256, 0, stream>>>(xb, wqb, wkb, wvb, qb, kb, vtb);
  scan_mask_kernel<<<1, 256, 0, stream>>>(mask, firstone);
  mean_v_kernel<<<8192, 256, 0, stream>>>(vtb, meanv);
  flash_kernel<<<dim3(16, 16, 4), 256, 0, stream>>>(qb, kb, vtb, maskadd, attnb);
  fixup_kernel<<<dim3(4, 16), 128, 0, stream>>>(firstone, meanv, attnb);
  out_gemm_kernel<<<dim3(16, 32), 256, 0, stream>>>(attnb, wob, out);
}

// Round 4
// 658.863 us; speedup vs baseline: 1.9933x; 1.0471x over previous
//
#include <hip/hip_runtime.h>

typedef __bf16 bf16;
typedef __bf16 bf16x4 __attribute__((ext_vector_type(4)));
typedef __bf16 bf16x8 __attribute__((ext_vector_type(8)));
typedef float f32x4 __attribute__((ext_vector_type(4)));

#define NEGF (-1e9f)

// async global->LDS, 16B per lane. LDS dest must be wave-uniform-base + lane*16.
__device__ __forceinline__ void gload16(const void* g, void* l) {
  __builtin_amdgcn_global_load_lds(
      (__attribute__((address_space(1))) void*)(void*)g,
      (__attribute__((address_space(3))) void*)l, 16, 0, 0);
}

// ---------------------------------------------------------------------------
// prep: cast x and weights to bf16 (fold log2(e)/sqrt(dk) into w_q), build
// additive key-mask array; last block also computes firstone[b].
// ---------------------------------------------------------------------------
__global__ __launch_bounds__(256)
void prep_kernel(const float* __restrict__ x, const int* __restrict__ mask,
                 const float* __restrict__ wq, const float* __restrict__ wk,
                 const float* __restrict__ wv, const float* __restrict__ wo,
                 bf16* __restrict__ xb, bf16* __restrict__ wqb,
                 bf16* __restrict__ wkb, bf16* __restrict__ wvb,
                 bf16* __restrict__ wob, float* __restrict__ maskadd,
                 int* __restrict__ firstone)
{
  const float QS = 1.44269504f * 0.08838834764f;  // log2(e)/sqrt(128)
  const size_t i = ((size_t)blockIdx.x * 256 + threadIdx.x) * 4;
  if (i < (size_t)16777216) {
    const float4 v = *(const float4*)&x[i];
    bf16x4 o4 = {(bf16)v.x, (bf16)v.y, (bf16)v.z, (bf16)v.w};
    *(bf16x4*)&xb[i] = o4;
  }
  if (i < (size_t)4194304) {
    float4 v = *(const float4*)&wq[i];
    bf16x4 o4 = {(bf16)(v.x * QS), (bf16)(v.y * QS), (bf16)(v.z * QS), (bf16)(v.w * QS)};
    *(bf16x4*)&wqb[i] = o4;
    v = *(const float4*)&wk[i];
    bf16x4 o5 = {(bf16)v.x, (bf16)v.y, (bf16)v.z, (bf16)v.w};
    *(bf16x4*)&wkb[i] = o5;
    v = *(const float4*)&wv[i];
    bf16x4 o6 = {(bf16)v.x, (bf16)v.y, (bf16)v.z, (bf16)v.w};
    *(bf16x4*)&wvb[i] = o6;
    v = *(const float4*)&wo[i];
    bf16x4 o7 = {(bf16)v.x, (bf16)v.y, (bf16)v.z, (bf16)v.w};
    *(bf16x4*)&wob[i] = o7;
  }
  if (i < (size_t)8192) {
    const int4 m4 = *(const int4*)&mask[i];
    float4 o4 = {m4.x ? 0.f : NEGF, m4.y ? 0.f : NEGF,
                 m4.z ? 0.f : NEGF, m4.w ? 0.f : NEGF};
    *(float4*)&maskadd[i] = o4;
  }
  if (blockIdx.x == 16383) {   // per-batch first nonzero mask index
    __shared__ int fm;
    for (int b = 0; b < 4; ++b) {
      if (threadIdx.x == 0) fm = 2048;
      __syncthreads();
      int lm = 2048;
      for (int s = threadIdx.x; s < 2048; s += 256)
        if (mask[(b << 11) + s] != 0) lm = min(lm, s);
      atomicMin(&fm, lm);
      __syncthreads();
      if (threadIdx.x == 0) firstone[b] = fm;
      __syncthreads();
    }
  }
}

// ---------------------------------------------------------------------------
// GEMM core (m103 structure): C[128x128] = A @ Bt^T, bf16 in, fp32 acc.
// 4 waves x (64x64 wave tile), mfma_f32_16x16x32_bf16 4x4 frags, BK=64.
// 16-row fragment reads + XOR swizzle -> 2 lanes/bank (free).
// acc = 64 AGPR -> ~160 total regs -> 3 waves/SIMD.
// ---------------------------------------------------------------------------
__device__ __forceinline__ void gemm_core128(
    const bf16* __restrict__ A, const bf16* __restrict__ Bt, int K,
    int rowBase, int colBase, bf16* As, bf16* Bs, f32x4 acc[4][4])
{
  const int t = threadIdx.x;
  const int lane = t & 63;
  const int w = t >> 6;
  const int wm = (w >> 1) << 6;   // 0 / 64
  const int wn = (w & 1) << 6;    // 0 / 64
  const int l15 = lane & 15;
  const int quad = lane >> 4;

  for (int k0 = 0; k0 < K; k0 += 64) {
    __syncthreads();
#pragma unroll
    for (int i = 0; i < 4; ++i) {           // A tile: 128x64 bf16 = 16KB
      const int c = (i << 8) + t;
      const int row = c >> 3;
      const int col = ((c & 7) ^ (row & 7)) << 3;
      gload16(&A[(size_t)(rowBase + row) * K + k0 + col], &As[c << 3]);
    }
#pragma unroll
    for (int i = 0; i < 4; ++i) {           // B tile: 128x64 bf16 = 16KB
      const int c = (i << 8) + t;
      const int row = c >> 3;
      const int col = ((c & 7) ^ (row & 7)) << 3;
      gload16(&Bt[(size_t)(colBase + row) * K + k0 + col], &Bs[c << 3]);
    }
    __syncthreads();
#pragma unroll
    for (int ks = 0; ks < 2; ++ks) {        // 2 x k=32 steps
      bf16x8 a[4], b[4];
#pragma unroll
      for (int mi = 0; mi < 4; ++mi) {
        const int row = wm + (mi << 4) + l15;
        a[mi] = *(const bf16x8*)&As[(row << 6) + ((((ks << 2) + quad) ^ (row & 7)) << 3)];
      }
#pragma unroll
      for (int ni = 0; ni < 4; ++ni) {
        const int row = wn + (ni << 4) + l15;
        b[ni] = *(const bf16x8*)&Bs[(row << 6) + ((((ks << 2) + quad) ^ (row & 7)) << 3)];
      }
#pragma unroll
      for (int mi = 0; mi < 4; ++mi)
#pragma unroll
        for (int ni = 0; ni < 4; ++ni)
          acc[mi][ni] = __builtin_amdgcn_mfma_f32_16x16x32_bf16(
              a[mi], b[ni], acc[mi][ni], 0, 0, 0);
    }
  }
}

// QKV projection: x@W^T, epilogue scatters into per-head layouts:
//   z=0: Q -> [B,H,S,dk]   z=1: K -> [B,H,S,dk]   z=2: V -> [B,H,dk,S]
__global__ __launch_bounds__(256, 2)
void qkv_gemm_kernel(const bf16* __restrict__ xb,
                     const bf16* __restrict__ wqb, const bf16* __restrict__ wkb,
                     const bf16* __restrict__ wvb,
                     bf16* __restrict__ qb, bf16* __restrict__ kb,
                     bf16* __restrict__ vtb)
{
  __shared__ __align__(16) bf16 As[128 * 64];
  __shared__ __align__(16) bf16 Bs[128 * 64];
  const int z = blockIdx.z;
  const bf16* Bt = (z == 0) ? wqb : (z == 1) ? wkb : wvb;
  bf16* dst = (z == 0) ? qb : (z == 1) ? kb : vtb;
  const int rowBase = blockIdx.y << 7;
  const int colBase = blockIdx.x << 7;
  f32x4 acc[4][4];
#pragma unroll
  for (int mi = 0; mi < 4; ++mi)
#pragma unroll
    for (int ni = 0; ni < 4; ++ni)
#pragma unroll
      for (int r = 0; r < 4; ++r) acc[mi][ni][r] = 0.f;

  gemm_core128(xb, Bt, 2048, rowBase, colBase, As, Bs, acc);

  const int lane = threadIdx.x & 63;
  const int w = threadIdx.x >> 6;
  const int wm = (w >> 1) << 6;
  const int wn = (w & 1) << 6;
  const int l15 = lane & 15;
  const int quad = lane >> 4;
#pragma unroll
  for (int mi = 0; mi < 4; ++mi)
#pragma unroll
    for (int ni = 0; ni < 4; ++ni)
#pragma unroll
      for (int r = 0; r < 4; ++r) {
        const int row = rowBase + wm + (mi << 4) + (quad << 2) + r;
        const int col = colBase + wn + (ni << 4) + l15;
        const int b = row >> 11, s = row & 2047;
        const int h = col >> 7, d = col & 127;
        const bf16 v = (bf16)acc[mi][ni][r];
        if (z == 2) dst[((((b << 4) + h) << 7) + d) * 2048 + s] = v;
        else        dst[(((((b << 4) + h) << 11) + s) << 7) + d] = v;
      }
}

// final projection: attn @ w_o^T -> fp32 d_out
__global__ __launch_bounds__(256, 2)
void out_gemm_kernel(const bf16* __restrict__ attnb, const bf16* __restrict__ wob,
                     float* __restrict__ out)
{
  __shared__ __align__(16) bf16 As[128 * 64];
  __shared__ __align__(16) bf16 Bs[128 * 64];
  const int rowBase = blockIdx.y << 7;
  const int colBase = blockIdx.x << 7;
  f32x4 acc[4][4];
#pragma unroll
  for (int mi = 0; mi < 4; ++mi)
#pragma unroll
    for (int ni = 0; ni < 4; ++ni)
#pragma unroll
      for (int r = 0; r < 4; ++r) acc[mi][ni][r] = 0.f;

  gemm_core128(attnb, wob, 2048, rowBase, colBase, As, Bs, acc);

  const int lane = threadIdx.x & 63;
  const int w = threadIdx.x >> 6;
  const int wm = (w >> 1) << 6;
  const int wn = (w & 1) << 6;
  const int l15 = lane & 15;
  const int quad = lane >> 4;
#pragma unroll
  for (int mi = 0; mi < 4; ++mi)
#pragma unroll
    for (int ni = 0; ni < 4; ++ni)
#pragma unroll
      for (int r = 0; r < 4; ++r) {
        const int row = rowBase + wm + (mi << 4) + (quad << 2) + r;
        const int col = colBase + wn + (ni << 4) + l15;
        out[((size_t)row << 11) + col] = acc[mi][ni][r];
      }
}

// ---------------------------------------------------------------------------
// flash attention, fixed-max softmax (scores bounded -> m=0, no per-tile
// reductions). P-transpose buffer ALIASES the K-tile (extra barrier).
// LDS = 32KB. launch_bounds(256,2): 256-reg cap -> NO spill (the (256,4)
// variant spilled: 845MB scratch writes, 2.7x slower).
// ---------------------------------------------------------------------------
__global__ __launch_bounds__(256, 2)
void flash_kernel(const bf16* __restrict__ qb, const bf16* __restrict__ kb,
                  const bf16* __restrict__ vtb, const float* __restrict__ maskadd,
                  bf16* __restrict__ attnb)
{
  __shared__ __align__(16) bf16 Ks[64 * 128];   // K tile; re-used as P after QK
  __shared__ __align__(16) bf16 Vs[128 * 64];   // V^T tile

  const int qt = 15 - (int)blockIdx.x;          // long blocks first
  const int h = blockIdx.y, b = blockIdx.z;
  const int t = threadIdx.x, lane = t & 63, w = t >> 6;
  const int quad = lane >> 4, l15 = lane & 15;
  const int bh = (b << 4) + h;
  const bf16* Qp = qb + (size_t)bh * (2048 * 128);
  const bf16* Kp = kb + (size_t)bh * (2048 * 128);
  const bf16* Vp = vtb + (size_t)bh * (128 * 2048);
  const int qrow0 = (qt << 7) + (w << 5);

  // Q fragments (A layout: m=l15, k=quad*8+j), log2-scaled already
  bf16x8 qf[2][4];
#pragma unroll
  for (int mi = 0; mi < 2; ++mi)
#pragma unroll
    for (int kk = 0; kk < 4; ++kk)
      qf[mi][kk] = *(const bf16x8*)&Qp[((qrow0 + (mi << 4) + l15) << 7) + (kk << 5) + (quad << 3)];

  f32x4 o[2][8];
  float lpart[2][4];
#pragma unroll
  for (int mi = 0; mi < 2; ++mi)
#pragma unroll
    for (int r = 0; r < 4; ++r) lpart[mi][r] = 0.f;
#pragma unroll
  for (int mi = 0; mi < 2; ++mi)
#pragma unroll
    for (int dj = 0; dj < 8; ++dj)
#pragma unroll
      for (int r = 0; r < 4; ++r) o[mi][dj][r] = 0.f;

  bf16* Pw = &Ks[w << 11];   // per-wave 32x64 P region (stride 64, XOR swizzle)
  const int nkt = (qt << 1) + 2;
  for (int kt = 0; kt < nkt; ++kt) {
    __syncthreads();                        // prior P/V reads done
#pragma unroll
    for (int i = 0; i < 4; ++i) {           // K tile 64x128
      const int c = (i << 8) + t;
      const int row = c >> 4;
      const int col = ((c & 15) ^ (row & 15)) << 3;
      gload16(&Kp[(((kt << 6) + row) << 7) + col], &Ks[c << 3]);
    }
#pragma unroll
    for (int i = 0; i < 4; ++i) {           // V^T tile 128x64
      const int c = (i << 8) + t;
      const int row = c >> 3;
      const int col = ((c & 7) ^ (row & 7)) << 3;
      gload16(&Vp[(row << 11) + (kt << 6) + col], &Vs[c << 3]);
    }
    __syncthreads();                        // tiles visible

    const bool skip = (kt << 6) > qrow0 + 31;
    f32x4 S[2][4];
    if (!skip) {
      // S = Q @ K^T (log2 domain)
#pragma unroll
      for (int mi = 0; mi < 2; ++mi)
#pragma unroll
        for (int nj = 0; nj < 4; ++nj)
#pragma unroll
          for (int r = 0; r < 4; ++r) S[mi][nj][r] = 0.f;
#pragma unroll
      for (int kk = 0; kk < 4; ++kk) {
        bf16x8 kf[4];
#pragma unroll
        for (int nj = 0; nj < 4; ++nj) {
          const int key = (nj << 4) + l15;
          const int gd = (kk << 2) + quad;
          kf[nj] = *(const bf16x8*)&Ks[(key << 7) + ((gd ^ (key & 15)) << 3)];
        }
#pragma unroll
        for (int mi = 0; mi < 2; ++mi)
#pragma unroll
          for (int nj = 0; nj < 4; ++nj)
            S[mi][nj] = __builtin_amdgcn_mfma_f32_16x16x32_bf16(qf[mi][kk], kf[nj], S[mi][nj], 0, 0, 0);
      }
      // mask + causal + exp2 (m=0 fixed), accumulate l partials
      float mv[4];
#pragma unroll
      for (int nj = 0; nj < 4; ++nj)
        mv[nj] = maskadd[(b << 11) + (kt << 6) + (nj << 4) + l15];
      const bool diag = ((kt << 6) + 63 > qrow0);
#pragma unroll
      for (int mi = 0; mi < 2; ++mi)
#pragma unroll
        for (int nj = 0; nj < 4; ++nj)
#pragma unroll
          for (int r = 0; r < 4; ++r) {
            float s = S[mi][nj][r] + mv[nj];
            if (diag) {
              const int key = (kt << 6) + (nj << 4) + l15;
              const int qrow = qrow0 + (mi << 4) + (quad << 2) + r;
              if (key > qrow) s += NEGF;
            }
            const float p = __builtin_amdgcn_exp2f(s);
            S[mi][nj][r] = p;
            lpart[mi][r] += p;
          }
    }
    __syncthreads();                        // all waves done reading Ks
    if (!skip) {
      // P -> LDS (C-layout write, XOR-swizzled stride 64), wave-local
#pragma unroll
      for (int mi = 0; mi < 2; ++mi)
#pragma unroll
        for (int nj = 0; nj < 4; ++nj)
#pragma unroll
          for (int r = 0; r < 4; ++r) {
            const int row = (mi << 4) + (quad << 2) + r;
            const int col = (nj << 4) + l15;
            Pw[(row << 6) + ((((col >> 3) ^ (row & 7)) << 3) | (col & 7))] = (bf16)S[mi][nj][r];
          }
      // read back in A layout, PV mfmas
#pragma unroll
      for (int kk = 0; kk < 2; ++kk) {
        bf16x8 pf[2];
#pragma unroll
        for (int mi = 0; mi < 2; ++mi) {
          const int row = (mi << 4) + l15;
          pf[mi] = *(const bf16x8*)&Pw[(row << 6) + ((((kk << 2) + quad) ^ (row & 7)) << 3)];
        }
#pragma unroll
        for (int dj = 0; dj < 8; ++dj) {
          const int d = (dj << 4) + l15;
          const int gd = (kk << 2) + quad;
          const bf16x8 vf = *(const bf16x8*)&Vs[(d << 6) + ((gd ^ (d & 7)) << 3)];
#pragma unroll
          for (int mi = 0; mi < 2; ++mi)
            o[mi][dj] = __builtin_amdgcn_mfma_f32_16x16x32_bf16(pf[mi], vf, o[mi][dj], 0, 0, 0);
        }
      }
    }
  }

  // one-time l reduction across the 16 lanes holding each row's columns
#pragma unroll
  for (int mi = 0; mi < 2; ++mi)
#pragma unroll
    for (int r = 0; r < 4; ++r) {
      float s = lpart[mi][r];
#pragma unroll
      for (int off = 1; off < 16; off <<= 1) s += __shfl_xor(s, off);
      const float inv = 1.0f / s;   // l==0 rows produce NaN; fixup overwrites them
      const int row = qrow0 + (mi << 4) + (quad << 2) + r;
#pragma unroll
      for (int dj = 0; dj < 8; ++dj) {
        const int d = (dj << 4) + l15;
        attnb[((size_t)((b << 11) + row) << 11) + (h << 7) + d] = (bf16)(o[mi][dj][r] * inv);
      }
    }
}

// ---------------------------------------------------------------------------
// degenerate-row handling: rows q < first_nonzero(mask[b]) have ALL scores
// masked in the reference -> softmax uniform over all 2048 keys -> mean(V).
// ---------------------------------------------------------------------------
__global__ void mean_v_kernel(const bf16* __restrict__ vtb, float* __restrict__ meanv)
{
  const int row = blockIdx.x;  // bh*128 + d, 8192 rows
  float sum = 0.f;
  for (int s = threadIdx.x; s < 2048; s += 256)
    sum += (float)vtb[((size_t)row << 11) + s];
#pragma unroll
  for (int off = 1; off < 64; off <<= 1) sum += __shfl_xor(sum, off);
  __shared__ float part[4];
  if ((threadIdx.x & 63) == 0) part[threadIdx.x >> 6] = sum;
  __syncthreads();
  if (threadIdx.x == 0)
    meanv[row] = (part[0] + part[1] + part[2] + part[3]) * (1.0f / 2048.0f);
}

__global__ void fixup_kernel(const int* __restrict__ firstone,
                             const float* __restrict__ meanv,
                             bf16* __restrict__ attnb)
{
  const int b = blockIdx.x, h = blockIdx.y, d = threadIdx.x;  // 128 threads
  const int f = firstone[b];
  const bf16 v = (bf16)meanv[(((b << 4) + h) << 7) + d];
  for (int s = 0; s < f; ++s)
    attnb[((size_t)((b << 11) + s) << 11) + (h << 7) + d] = v;
}

// ---------------------------------------------------------------------------
extern "C" void kernel_launch(void* const* d_in, const int* in_sizes, int n_in,
                              void* d_out, int out_size, void* d_ws, size_t ws_size,
                              hipStream_t stream)
{
  const float* x  = (const float*)d_in[0];
  const int* mask = (const int*)d_in[1];
  const float* wq = (const float*)d_in[2];
  const float* wk = (const float*)d_in[3];
  const float* wv = (const float*)d_in[4];
  const float* wo = (const float*)d_in[5];
  float* out = (float*)d_out;

  char* ws = (char*)d_ws;
  bf16* xb      = (bf16*)(ws + 0);            // 33554432
  bf16* wqb     = (bf16*)(ws + 33554432);     //  8388608
  bf16* wkb     = (bf16*)(ws + 41943040);     //  8388608
  bf16* wvb     = (bf16*)(ws + 50331648);     //  8388608
  bf16* wob     = (bf16*)(ws + 58720256);     //  8388608
  bf16* qb      = (bf16*)(ws + 67108864);     // 33554432
  bf16* kb      = (bf16*)(ws + 100663296);    // 33554432
  bf16* vtb     = (bf16*)(ws + 134217728);    // 33554432
  bf16* attnb   = (bf16*)(ws + 167772160);    // 33554432
  float* maskadd= (float*)(ws + 201326592);   //    32768
  float* meanv  = (float*)(ws + 201359360);   //    32768
  int* firstone = (int*)(ws + 201392128);     //       16

  prep_kernel<<<16384, 256, 0, stream>>>(x, mask, wq, wk, wv, wo,
                                         xb, wqb, wkb, wvb, wob, maskadd, firstone);
  qkv_gemm_kernel<<<dim3(16, 64, 3), 256, 0, stream>>>(xb, wqb, wkb, wvb, qb, kb, vtb);
  mean_v_kernel<<<8192, 256, 0, stream>>>(vtb, meanv);
  flash_kernel<<<dim3(16, 16, 4), 256, 0, stream>>>(qb, kb, vtb, maskadd, attnb);
  fixup_kernel<<<dim3(4, 16), 128, 0, stream>>>(firstone, meanv, attnb);
  out_gemm_kernel<<<dim3(16, 64), 256, 0, stream>>>(attnb, wob, out);
}

// Round 5
// 616.741 us; speedup vs baseline: 2.1295x; 1.0683x over previous
//
#include <hip/hip_runtime.h>

typedef __bf16 bf16;
typedef __bf16 bf16x4 __attribute__((ext_vector_type(4)));
typedef __bf16 bf16x8 __attribute__((ext_vector_type(8)));
typedef float f32x4 __attribute__((ext_vector_type(4)));

#define NEGF (-1e9f)

// async global->LDS, 16B per lane. LDS dest must be wave-uniform-base + lane*16.
__device__ __forceinline__ void gload16(const void* g, void* l) {
  __builtin_amdgcn_global_load_lds(
      (__attribute__((address_space(1))) void*)(void*)g,
      (__attribute__((address_space(3))) void*)l, 16, 0, 0);
}

// ---------------------------------------------------------------------------
// prep: cast x and weights to bf16 (fold log2(e)/sqrt(dk) into w_q), build
// additive key-mask array; last block also computes firstone[b].
// ---------------------------------------------------------------------------
__global__ __launch_bounds__(256)
void prep_kernel(const float* __restrict__ x, const int* __restrict__ mask,
                 const float* __restrict__ wq, const float* __restrict__ wk,
                 const float* __restrict__ wv, const float* __restrict__ wo,
                 bf16* __restrict__ xb, bf16* __restrict__ wqb,
                 bf16* __restrict__ wkb, bf16* __restrict__ wvb,
                 bf16* __restrict__ wob, float* __restrict__ maskadd,
                 int* __restrict__ firstone)
{
  const float QS = 1.44269504f * 0.08838834764f;  // log2(e)/sqrt(128)
  const size_t i = ((size_t)blockIdx.x * 256 + threadIdx.x) * 4;
  if (i < (size_t)16777216) {
    const float4 v = *(const float4*)&x[i];
    bf16x4 o4 = {(bf16)v.x, (bf16)v.y, (bf16)v.z, (bf16)v.w};
    *(bf16x4*)&xb[i] = o4;
  }
  if (i < (size_t)4194304) {
    float4 v = *(const float4*)&wq[i];
    bf16x4 o4 = {(bf16)(v.x * QS), (bf16)(v.y * QS), (bf16)(v.z * QS), (bf16)(v.w * QS)};
    *(bf16x4*)&wqb[i] = o4;
    v = *(const float4*)&wk[i];
    bf16x4 o5 = {(bf16)v.x, (bf16)v.y, (bf16)v.z, (bf16)v.w};
    *(bf16x4*)&wkb[i] = o5;
    v = *(const float4*)&wv[i];
    bf16x4 o6 = {(bf16)v.x, (bf16)v.y, (bf16)v.z, (bf16)v.w};
    *(bf16x4*)&wvb[i] = o6;
    v = *(const float4*)&wo[i];
    bf16x4 o7 = {(bf16)v.x, (bf16)v.y, (bf16)v.z, (bf16)v.w};
    *(bf16x4*)&wob[i] = o7;
  }
  if (i < (size_t)8192) {
    const int4 m4 = *(const int4*)&mask[i];
    float4 o4 = {m4.x ? 0.f : NEGF, m4.y ? 0.f : NEGF,
                 m4.z ? 0.f : NEGF, m4.w ? 0.f : NEGF};
    *(float4*)&maskadd[i] = o4;
  }
  if (blockIdx.x == 16383) {   // per-batch first nonzero mask index
    __shared__ int fm;
    for (int b = 0; b < 4; ++b) {
      if (threadIdx.x == 0) fm = 2048;
      __syncthreads();
      int lm = 2048;
      for (int s = threadIdx.x; s < 2048; s += 256)
        if (mask[(b << 11) + s] != 0) lm = min(lm, s);
      atomicMin(&fm, lm);
      __syncthreads();
      if (threadIdx.x == 0) firstone[b] = fm;
      __syncthreads();
    }
  }
}

// ---------------------------------------------------------------------------
// GEMM core (m103 structure): C[128x128] = A @ Bt^T, bf16 in, fp32 acc.
// 4 waves x (64x64 wave tile), mfma_f32_16x16x32_bf16 4x4 frags, BK=64.
// 16-row fragment reads + XOR swizzle -> 2 lanes/bank (free).
// ---------------------------------------------------------------------------
__device__ __forceinline__ void gemm_core128(
    const bf16* __restrict__ A, const bf16* __restrict__ Bt, int K,
    int rowBase, int colBase, bf16* As, bf16* Bs, f32x4 acc[4][4])
{
  const int t = threadIdx.x;
  const int lane = t & 63;
  const int w = t >> 6;
  const int wm = (w >> 1) << 6;   // 0 / 64
  const int wn = (w & 1) << 6;    // 0 / 64
  const int l15 = lane & 15;
  const int quad = lane >> 4;

  for (int k0 = 0; k0 < K; k0 += 64) {
    __syncthreads();
#pragma unroll
    for (int i = 0; i < 4; ++i) {           // A tile: 128x64 bf16 = 16KB
      const int c = (i << 8) + t;
      const int row = c >> 3;
      const int col = ((c & 7) ^ (row & 7)) << 3;
      gload16(&A[(size_t)(rowBase + row) * K + k0 + col], &As[c << 3]);
    }
#pragma unroll
    for (int i = 0; i < 4; ++i) {           // B tile: 128x64 bf16 = 16KB
      const int c = (i << 8) + t;
      const int row = c >> 3;
      const int col = ((c & 7) ^ (row & 7)) << 3;
      gload16(&Bt[(size_t)(colBase + row) * K + k0 + col], &Bs[c << 3]);
    }
    __syncthreads();
#pragma unroll
    for (int ks = 0; ks < 2; ++ks) {        // 2 x k=32 steps
      bf16x8 a[4], b[4];
#pragma unroll
      for (int mi = 0; mi < 4; ++mi) {
        const int row = wm + (mi << 4) + l15;
        a[mi] = *(const bf16x8*)&As[(row << 6) + ((((ks << 2) + quad) ^ (row & 7)) << 3)];
      }
#pragma unroll
      for (int ni = 0; ni < 4; ++ni) {
        const int row = wn + (ni << 4) + l15;
        b[ni] = *(const bf16x8*)&Bs[(row << 6) + ((((ks << 2) + quad) ^ (row & 7)) << 3)];
      }
#pragma unroll
      for (int mi = 0; mi < 4; ++mi)
#pragma unroll
        for (int ni = 0; ni < 4; ++ni)
          acc[mi][ni] = __builtin_amdgcn_mfma_f32_16x16x32_bf16(
              a[mi], b[ni], acc[mi][ni], 0, 0, 0);
    }
  }
}

// QKV projection: x@W^T, epilogue scatters into per-head layouts:
//   z=0: Q -> [B,H,S,dk]   z=1: K -> [B,H,S,dk]   z=2: V -> [B,H,dk,S]
__global__ __launch_bounds__(256, 2)
void qkv_gemm_kernel(const bf16* __restrict__ xb,
                     const bf16* __restrict__ wqb, const bf16* __restrict__ wkb,
                     const bf16* __restrict__ wvb,
                     bf16* __restrict__ qb, bf16* __restrict__ kb,
                     bf16* __restrict__ vtb)
{
  __shared__ __align__(16) bf16 As[128 * 64];
  __shared__ __align__(16) bf16 Bs[128 * 64];
  const int z = blockIdx.z;
  const bf16* Bt = (z == 0) ? wqb : (z == 1) ? wkb : wvb;
  bf16* dst = (z == 0) ? qb : (z == 1) ? kb : vtb;
  const int rowBase = blockIdx.y << 7;
  const int colBase = blockIdx.x << 7;
  f32x4 acc[4][4];
#pragma unroll
  for (int mi = 0; mi < 4; ++mi)
#pragma unroll
    for (int ni = 0; ni < 4; ++ni)
#pragma unroll
      for (int r = 0; r < 4; ++r) acc[mi][ni][r] = 0.f;

  gemm_core128(xb, Bt, 2048, rowBase, colBase, As, Bs, acc);

  const int lane = threadIdx.x & 63;
  const int w = threadIdx.x >> 6;
  const int wm = (w >> 1) << 6;
  const int wn = (w & 1) << 6;
  const int l15 = lane & 15;
  const int quad = lane >> 4;
#pragma unroll
  for (int mi = 0; mi < 4; ++mi)
#pragma unroll
    for (int ni = 0; ni < 4; ++ni)
#pragma unroll
      for (int r = 0; r < 4; ++r) {
        const int row = rowBase + wm + (mi << 4) + (quad << 2) + r;
        const int col = colBase + wn + (ni << 4) + l15;
        const int b = row >> 11, s = row & 2047;
        const int h = col >> 7, d = col & 127;
        const bf16 v = (bf16)acc[mi][ni][r];
        if (z == 2) dst[((((b << 4) + h) << 7) + d) * 2048 + s] = v;
        else        dst[(((((b << 4) + h) << 11) + s) << 7) + d] = v;
      }
}

// final projection: attn @ w_o^T -> fp32 d_out
__global__ __launch_bounds__(256, 2)
void out_gemm_kernel(const bf16* __restrict__ attnb, const bf16* __restrict__ wob,
                     float* __restrict__ out)
{
  __shared__ __align__(16) bf16 As[128 * 64];
  __shared__ __align__(16) bf16 Bs[128 * 64];
  const int rowBase = blockIdx.y << 7;
  const int colBase = blockIdx.x << 7;
  f32x4 acc[4][4];
#pragma unroll
  for (int mi = 0; mi < 4; ++mi)
#pragma unroll
    for (int ni = 0; ni < 4; ++ni)
#pragma unroll
      for (int r = 0; r < 4; ++r) acc[mi][ni][r] = 0.f;

  gemm_core128(attnb, wob, 2048, rowBase, colBase, As, Bs, acc);

  const int lane = threadIdx.x & 63;
  const int w = threadIdx.x >> 6;
  const int wm = (w >> 1) << 6;
  const int wn = (w & 1) << 6;
  const int l15 = lane & 15;
  const int quad = lane >> 4;
#pragma unroll
  for (int mi = 0; mi < 4; ++mi)
#pragma unroll
    for (int ni = 0; ni < 4; ++ni)
#pragma unroll
      for (int r = 0; r < 4; ++r) {
        const int row = rowBase + wm + (mi << 4) + (quad << 2) + r;
        const int col = colBase + wn + (ni << 4) + l15;
        out[((size_t)row << 11) + col] = acc[mi][ni][r];
      }
}

// ---------------------------------------------------------------------------
// flash attention, fixed-max softmax (m=0). P-transpose aliases the K-tile.
// LDS = 32KB, 4 blocks/CU co-resident (whole 1024-block grid).
// CU-balanced qt mapping: CU c receives blocks {c, c+256, c+512, c+768}
// (round-robin), whose z = 0..3. qt = (z&1) ? x : 15-x gives that CU
// qt = {x, 15-x, x, 15-x} -> per-CU work = 68 k-tile units, CONSTANT.
// (qt from x alone put 4 same-qt blocks per CU: hottest CU did 128 units.)
// ---------------------------------------------------------------------------
__global__ __launch_bounds__(256, 2)
void flash_kernel(const bf16* __restrict__ qb, const bf16* __restrict__ kb,
                  const bf16* __restrict__ vtb, const float* __restrict__ maskadd,
                  bf16* __restrict__ attnb)
{
  __shared__ __align__(16) bf16 Ks[64 * 128];   // K tile; re-used as P after QK
  __shared__ __align__(16) bf16 Vs[128 * 64];   // V^T tile

  const int h = blockIdx.y, b = blockIdx.z;
  const int qt = (b & 1) ? (int)blockIdx.x : 15 - (int)blockIdx.x;
  const int t = threadIdx.x, lane = t & 63, w = t >> 6;
  const int quad = lane >> 4, l15 = lane & 15;
  const int bh = (b << 4) + h;
  const bf16* Qp = qb + (size_t)bh * (2048 * 128);
  const bf16* Kp = kb + (size_t)bh * (2048 * 128);
  const bf16* Vp = vtb + (size_t)bh * (128 * 2048);
  const int qrow0 = (qt << 7) + (w << 5);

  // Q fragments (A layout: m=l15, k=quad*8+j), log2-scaled already
  bf16x8 qf[2][4];
#pragma unroll
  for (int mi = 0; mi < 2; ++mi)
#pragma unroll
    for (int kk = 0; kk < 4; ++kk)
      qf[mi][kk] = *(const bf16x8*)&Qp[((qrow0 + (mi << 4) + l15) << 7) + (kk << 5) + (quad << 3)];

  f32x4 o[2][8];
  float lpart[2][4];
#pragma unroll
  for (int mi = 0; mi < 2; ++mi)
#pragma unroll
    for (int r = 0; r < 4; ++r) lpart[mi][r] = 0.f;
#pragma unroll
  for (int mi = 0; mi < 2; ++mi)
#pragma unroll
    for (int dj = 0; dj < 8; ++dj)
#pragma unroll
      for (int r = 0; r < 4; ++r) o[mi][dj][r] = 0.f;

  bf16* Pw = &Ks[w << 11];   // per-wave 32x64 P region (stride 64, XOR swizzle)
  const int nkt = (qt << 1) + 2;
  for (int kt = 0; kt < nkt; ++kt) {
    __syncthreads();                        // prior P/V reads done
#pragma unroll
    for (int i = 0; i < 4; ++i) {           // K tile 64x128
      const int c = (i << 8) + t;
      const int row = c >> 4;
      const int col = ((c & 15) ^ (row & 15)) << 3;
      gload16(&Kp[(((kt << 6) + row) << 7) + col], &Ks[c << 3]);
    }
#pragma unroll
    for (int i = 0; i < 4; ++i) {           // V^T tile 128x64
      const int c = (i << 8) + t;
      const int row = c >> 3;
      const int col = ((c & 7) ^ (row & 7)) << 3;
      gload16(&Vp[(row << 11) + (kt << 6) + col], &Vs[c << 3]);
    }
    __syncthreads();                        // tiles visible

    const bool skip = (kt << 6) > qrow0 + 31;
    f32x4 S[2][4];
    if (!skip) {
      // S = Q @ K^T (log2 domain)
#pragma unroll
      for (int mi = 0; mi < 2; ++mi)
#pragma unroll
        for (int nj = 0; nj < 4; ++nj)
#pragma unroll
          for (int r = 0; r < 4; ++r) S[mi][nj][r] = 0.f;
#pragma unroll
      for (int kk = 0; kk < 4; ++kk) {
        bf16x8 kf[4];
#pragma unroll
        for (int nj = 0; nj < 4; ++nj) {
          const int key = (nj << 4) + l15;
          const int gd = (kk << 2) + quad;
          kf[nj] = *(const bf16x8*)&Ks[(key << 7) + ((gd ^ (key & 15)) << 3)];
        }
#pragma unroll
        for (int mi = 0; mi < 2; ++mi)
#pragma unroll
          for (int nj = 0; nj < 4; ++nj)
            S[mi][nj] = __builtin_amdgcn_mfma_f32_16x16x32_bf16(qf[mi][kk], kf[nj], S[mi][nj], 0, 0, 0);
      }
      // mask + causal + exp2 (m=0 fixed), accumulate l partials
      float mv[4];
#pragma unroll
      for (int nj = 0; nj < 4; ++nj)
        mv[nj] = maskadd[(b << 11) + (kt << 6) + (nj << 4) + l15];
      const bool diag = ((kt << 6) + 63 > qrow0);
#pragma unroll
      for (int mi = 0; mi < 2; ++mi)
#pragma unroll
        for (int nj = 0; nj < 4; ++nj)
#pragma unroll
          for (int r = 0; r < 4; ++r) {
            float s = S[mi][nj][r] + mv[nj];
            if (diag) {
              const int key = (kt << 6) + (nj << 4) + l15;
              const int qrow = qrow0 + (mi << 4) + (quad << 2) + r;
              if (key > qrow) s += NEGF;
            }
            const float p = __builtin_amdgcn_exp2f(s);
            S[mi][nj][r] = p;
            lpart[mi][r] += p;
          }
    }
    __syncthreads();                        // all waves done reading Ks
    if (!skip) {
      // P -> LDS (C-layout write, XOR-swizzled stride 64), wave-local
#pragma unroll
      for (int mi = 0; mi < 2; ++mi)
#pragma unroll
        for (int nj = 0; nj < 4; ++nj)
#pragma unroll
          for (int r = 0; r < 4; ++r) {
            const int row = (mi << 4) + (quad << 2) + r;
            const int col = (nj << 4) + l15;
            Pw[(row << 6) + ((((col >> 3) ^ (row & 7)) << 3) | (col & 7))] = (bf16)S[mi][nj][r];
          }
      // read back in A layout, PV mfmas
#pragma unroll
      for (int kk = 0; kk < 2; ++kk) {
        bf16x8 pf[2];
#pragma unroll
        for (int mi = 0; mi < 2; ++mi) {
          const int row = (mi << 4) + l15;
          pf[mi] = *(const bf16x8*)&Pw[(row << 6) + ((((kk << 2) + quad) ^ (row & 7)) << 3)];
        }
#pragma unroll
        for (int dj = 0; dj < 8; ++dj) {
          const int d = (dj << 4) + l15;
          const int gd = (kk << 2) + quad;
          const bf16x8 vf = *(const bf16x8*)&Vs[(d << 6) + ((gd ^ (d & 7)) << 3)];
#pragma unroll
          for (int mi = 0; mi < 2; ++mi)
            o[mi][dj] = __builtin_amdgcn_mfma_f32_16x16x32_bf16(pf[mi], vf, o[mi][dj], 0, 0, 0);
        }
      }
    }
  }

  // one-time l reduction across the 16 lanes holding each row's columns
#pragma unroll
  for (int mi = 0; mi < 2; ++mi)
#pragma unroll
    for (int r = 0; r < 4; ++r) {
      float s = lpart[mi][r];
#pragma unroll
      for (int off = 1; off < 16; off <<= 1) s += __shfl_xor(s, off);
      const float inv = 1.0f / s;   // l==0 rows produce NaN; fixup overwrites them
      const int row = qrow0 + (mi << 4) + (quad << 2) + r;
#pragma unroll
      for (int dj = 0; dj < 8; ++dj) {
        const int d = (dj << 4) + l15;
        attnb[((size_t)((b << 11) + row) << 11) + (h << 7) + d] = (bf16)(o[mi][dj][r] * inv);
      }
    }
}

// ---------------------------------------------------------------------------
// degenerate-row handling: rows q < first_nonzero(mask[b]) have ALL scores
// masked in the reference -> softmax uniform over all 2048 keys -> mean(V).
// ---------------------------------------------------------------------------
__global__ void mean_v_kernel(const bf16* __restrict__ vtb, float* __restrict__ meanv)
{
  const int row = blockIdx.x;  // bh*128 + d, 8192 rows
  float sum = 0.f;
  for (int s = threadIdx.x; s < 2048; s += 256)
    sum += (float)vtb[((size_t)row << 11) + s];
#pragma unroll
  for (int off = 1; off < 64; off <<= 1) sum += __shfl_xor(sum, off);
  __shared__ float part[4];
  if ((threadIdx.x & 63) == 0) part[threadIdx.x >> 6] = sum;
  __syncthreads();
  if (threadIdx.x == 0)
    meanv[row] = (part[0] + part[1] + part[2] + part[3]) * (1.0f / 2048.0f);
}

__global__ void fixup_kernel(const int* __restrict__ firstone,
                             const float* __restrict__ meanv,
                             bf16* __restrict__ attnb)
{
  const int b = blockIdx.x, h = blockIdx.y, d = threadIdx.x;  // 128 threads
  const int f = firstone[b];
  const bf16 v = (bf16)meanv[(((b << 4) + h) << 7) + d];
  for (int s = 0; s < f; ++s)
    attnb[((size_t)((b << 11) + s) << 11) + (h << 7) + d] = v;
}

// ---------------------------------------------------------------------------
extern "C" void kernel_launch(void* const* d_in, const int* in_sizes, int n_in,
                              void* d_out, int out_size, void* d_ws, size_t ws_size,
                              hipStream_t stream)
{
  const float* x  = (const float*)d_in[0];
  const int* mask = (const int*)d_in[1];
  const float* wq = (const float*)d_in[2];
  const float* wk = (const float*)d_in[3];
  const float* wv = (const float*)d_in[4];
  const float* wo = (const float*)d_in[5];
  float* out = (float*)d_out;

  char* ws = (char*)d_ws;
  bf16* xb      = (bf16*)(ws + 0);            // 33554432
  bf16* wqb     = (bf16*)(ws + 33554432);     //  8388608
  bf16* wkb     = (bf16*)(ws + 41943040);     //  8388608
  bf16* wvb     = (bf16*)(ws + 50331648);     //  8388608
  bf16* wob     = (bf16*)(ws + 58720256);     //  8388608
  bf16* qb      = (bf16*)(ws + 67108864);     // 33554432
  bf16* kb      = (bf16*)(ws + 100663296);    // 33554432
  bf16* vtb     = (bf16*)(ws + 134217728);    // 33554432
  bf16* attnb   = (bf16*)(ws + 167772160);    // 33554432
  float* maskadd= (float*)(ws + 201326592);   //    32768
  float* meanv  = (float*)(ws + 201359360);   //    32768
  int* firstone = (int*)(ws + 201392128);     //       16

  prep_kernel<<<16384, 256, 0, stream>>>(x, mask, wq, wk, wv, wo,
                                         xb, wqb, wkb, wvb, wob, maskadd, firstone);
  qkv_gemm_kernel<<<dim3(16, 64, 3), 256, 0, stream>>>(xb, wqb, wkb, wvb, qb, kb, vtb);
  mean_v_kernel<<<8192, 256, 0, stream>>>(vtb, meanv);
  flash_kernel<<<dim3(16, 16, 4), 256, 0, stream>>>(qb, kb, vtb, maskadd, attnb);
  fixup_kernel<<<dim3(4, 16), 128, 0, stream>>>(firstone, meanv, attnb);
  out_gemm_kernel<<<dim3(16, 64), 256, 0, stream>>>(attnb, wob, out);
}